// Round 4
// baseline (450.888 us; speedup 1.0000x reference)
//
#include <hip/hip_runtime.h>

#define C_NUM   256
#define K_CODES 4096
#define D_CB    8
#define THREADS 1024
#define WAVES   16
#define TPW     16                  // tuples per wave
#define HALF_CODES (K_CODES / 2)    // each wave-group scans 2048 codes
#define CHUNKS  (HALF_CODES / 64)   // 32 chunks of 64 codes (one per lane)

__global__ __launch_bounds__(THREADS)
void dkvb_kernel(const float* __restrict__ emb,
                 const float* __restrict__ keys,
                 const float* __restrict__ values,
                 float* __restrict__ out) {
    __shared__ float xs[128][D_CB];      // 4 KB
    __shared__ float dL[WAVES][TPW];     // 1 KB
    __shared__ int   iL[WAVES][TPW];     // 1 KB

    const int c    = blockIdx.x;
    const int tid  = threadIdx.x;
    const int wave = tid >> 6;
    const int lane = tid & 63;
    const int grp  = wave >> 3;          // 0: codes 0..2047, 1: 2048..4095
    const int wtup = wave & 7;           // which 16-tuple slice

    // ---- stage x into LDS: one element per thread ----
    // x[t][j] = emb[(t>>4)*32768 + c*128 + j*16 + (t&15)]
    {
        const int t = tid >> 3, j = tid & 7;
        xs[t][j] = emb[(size_t)(t >> 4) * 32768 + c * 128 + j * 16 + (t & 15)];
    }
    __syncthreads();

    // ---- wave-uniform x + x2 (bitwise-identical chain to R1/R2) ----
    float x[TPW][8];
    float x2[TPW];
    #pragma unroll
    for (int t = 0; t < TPW; ++t) {
        #pragma unroll
        for (int j = 0; j < 8; ++j) x[t][j] = xs[wtup * TPW + t][j];
        float s = x[t][0] * x[t][0];
        #pragma unroll
        for (int j = 1; j < 8; ++j) s = fmaf(x[t][j], x[t][j], s);
        x2[t] = s;
    }

    float bestd[TPW];
    int   besti[TPW];
    #pragma unroll
    for (int t = 0; t < TPW; ++t) { bestd[t] = 3.4028235e38f; besti[t] = 0; }

    // ---- scan this group's 2048 codes; lane l owns codes {base+l, base+64+l, ...} ----
    const float4* kb = (const float4*)(keys + (size_t)c * K_CODES * D_CB);
    const int basef4 = grp * (HALF_CODES * 2);        // float4 index of group base
    float4 a0 = kb[basef4 + lane * 2];
    float4 a1 = kb[basef4 + lane * 2 + 1];
    for (int ch = 0; ch < CHUNKS; ++ch) {
        const int nc = (ch + 1 < CHUNKS) ? (ch + 1) : ch;
        const float4 b0 = kb[basef4 + nc * 128 + lane * 2];
        const float4 b1 = kb[basef4 + nc * 128 + lane * 2 + 1];

        const int code = grp * HALF_CODES + ch * 64 + lane;
        float k2 = a0.x * a0.x;
        k2 = fmaf(a0.y, a0.y, k2);
        k2 = fmaf(a0.z, a0.z, k2);
        k2 = fmaf(a0.w, a0.w, k2);
        k2 = fmaf(a1.x, a1.x, k2);
        k2 = fmaf(a1.y, a1.y, k2);
        k2 = fmaf(a1.z, a1.z, k2);
        k2 = fmaf(a1.w, a1.w, k2);

        #pragma unroll
        for (int t = 0; t < TPW; ++t) {
            float d = x[t][0] * a0.x;
            d = fmaf(x[t][1], a0.y, d);
            d = fmaf(x[t][2], a0.z, d);
            d = fmaf(x[t][3], a0.w, d);
            d = fmaf(x[t][4], a1.x, d);
            d = fmaf(x[t][5], a1.y, d);
            d = fmaf(x[t][6], a1.z, d);
            d = fmaf(x[t][7], a1.w, d);
            const float dist = fmaf(d, -2.0f, x2[t] + k2);
            const bool lt = dist < bestd[t];
            bestd[t] = lt ? dist : bestd[t];
            besti[t] = lt ? code : besti[t];
        }
        a0 = b0; a1 = b1;
    }

    // ---- cross-lane argmin per tuple (tie -> smaller index) ----
    float myd = 0.0f;
    int   myidx = 0;
    #pragma unroll
    for (int t = 0; t < TPW; ++t) {
        float d = bestd[t];
        int   i = besti[t];
        #pragma unroll
        for (int m = 32; m >= 1; m >>= 1) {
            const float od = __shfl_xor(d, m, 64);
            const int   oi = __shfl_xor(i, m, 64);
            if (od < d || (od == d && oi < i)) { d = od; i = oi; }
        }
        if (lane == t) { myd = d; myidx = i; }
    }

    // ---- cross-group combine via LDS ----
    if (lane < TPW) { dL[wave][lane] = myd; iL[wave][lane] = myidx; }
    __syncthreads();

    if (grp == 0 && lane < TPW) {
        const float d0 = dL[wave][lane];
        const float d1 = dL[wave + 8][lane];
        // group 1 codes are all larger; exact tie keeps group 0 (numpy tie-break)
        const int idx = (d1 < d0) ? iL[wave + 8][lane] : iL[wave][lane];

        const int tg = wtup * TPW + lane;           // tuple = b*16 + n
        const int b = tg >> 4, n = tg & 15;
        const float4* vr = (const float4*)(values + ((size_t)c * K_CODES + idx) * D_CB);
        const float4 v0 = vr[0];
        const float4 v1 = vr[1];
        float* op = out + (size_t)b * 32768 + c * 128 + n;
        op[0]   = v0.x; op[16]  = v0.y; op[32]  = v0.z; op[48]  = v0.w;
        op[64]  = v1.x; op[80]  = v1.y; op[96]  = v1.z; op[112] = v1.w;
    }
}

extern "C" void kernel_launch(void* const* d_in, const int* in_sizes, int n_in,
                              void* d_out, int out_size, void* d_ws, size_t ws_size,
                              hipStream_t stream) {
    const float* emb    = (const float*)d_in[0];
    const float* keys   = (const float*)d_in[1];
    const float* values = (const float*)d_in[2];
    float* out = (float*)d_out;
    dkvb_kernel<<<C_NUM, THREADS, 0, stream>>>(emb, keys, values, out);
}

// Round 5
// 49.142 us; speedup vs baseline: 9.1752x; 9.1752x over previous
//
#include <hip/hip_runtime.h>

#define C_NUM   256
#define K_CODES 4096
#define D_CB    8
#define THREADS 512
#define WAVES   8
#define TPW     8                   // tuples per wave (64 tuples/block, 8 waves)
#define CHUNKS  (K_CODES / 64)      // 64 chunks of 64 codes (one per lane)

__global__ __launch_bounds__(THREADS, 2)
void dkvb_kernel(const float* __restrict__ emb,
                 const float* __restrict__ keys,
                 const float* __restrict__ values,
                 float* __restrict__ out) {
    __shared__ float xs[64][D_CB];   // 2 KB

    const int bid  = blockIdx.x;
    const int c    = bid & 255;      // codebook; bid and bid+256 share XCD (256%8==0)
    const int h    = bid >> 8;       // tuple half: 0 -> tuples 0..63, 1 -> 64..127
    const int tid  = threadIdx.x;
    const int wave = tid >> 6;
    const int lane = tid & 63;

    // ---- stage this block's 64 tuples of x into LDS (one element/thread) ----
    // x[t][j] = emb[(t>>4)*32768 + c*128 + j*16 + (t&15)]
    {
        const int tl = tid >> 3, j = tid & 7;
        const int tg = h * 64 + tl;
        xs[tl][j] = emb[(size_t)(tg >> 4) * 32768 + c * 128 + j * 16 + (tg & 15)];
    }
    __syncthreads();

    // ---- wave-uniform x + x2 (bitwise-identical chain to R1/R2) ----
    float x[TPW][8];
    float x2[TPW];
    #pragma unroll
    for (int t = 0; t < TPW; ++t) {
        #pragma unroll
        for (int j = 0; j < 8; ++j) x[t][j] = xs[wave * TPW + t][j];
        float s = x[t][0] * x[t][0];
        #pragma unroll
        for (int j = 1; j < 8; ++j) s = fmaf(x[t][j], x[t][j], s);
        x2[t] = s;
    }

    float bestd[TPW];
    int   besti[TPW];
    #pragma unroll
    for (int t = 0; t < TPW; ++t) { bestd[t] = 3.4028235e38f; besti[t] = 0; }

    // ---- scan all 4096 codes; lane l owns codes {l, 64+l, ...} ----
    const float4* kb = (const float4*)(keys + (size_t)c * K_CODES * D_CB);
    float4 a0 = kb[lane * 2];
    float4 a1 = kb[lane * 2 + 1];
    for (int ch = 0; ch < CHUNKS; ++ch) {
        const int nc = (ch + 1 < CHUNKS) ? (ch + 1) : ch;
        const float4 b0 = kb[nc * 128 + lane * 2];
        const float4 b1 = kb[nc * 128 + lane * 2 + 1];

        const int code = ch * 64 + lane;
        float k2 = a0.x * a0.x;
        k2 = fmaf(a0.y, a0.y, k2);
        k2 = fmaf(a0.z, a0.z, k2);
        k2 = fmaf(a0.w, a0.w, k2);
        k2 = fmaf(a1.x, a1.x, k2);
        k2 = fmaf(a1.y, a1.y, k2);
        k2 = fmaf(a1.z, a1.z, k2);
        k2 = fmaf(a1.w, a1.w, k2);

        #pragma unroll
        for (int t = 0; t < TPW; ++t) {
            float d = x[t][0] * a0.x;
            d = fmaf(x[t][1], a0.y, d);
            d = fmaf(x[t][2], a0.z, d);
            d = fmaf(x[t][3], a0.w, d);
            d = fmaf(x[t][4], a1.x, d);
            d = fmaf(x[t][5], a1.y, d);
            d = fmaf(x[t][6], a1.z, d);
            d = fmaf(x[t][7], a1.w, d);
            const float dist = fmaf(d, -2.0f, x2[t] + k2);
            const bool lt = dist < bestd[t];
            bestd[t] = lt ? dist : bestd[t];
            besti[t] = lt ? code : besti[t];
        }
        a0 = b0; a1 = b1;
    }

    // ---- cross-lane argmin per tuple (tie -> smaller index == numpy) ----
    int myidx = 0;
    #pragma unroll
    for (int t = 0; t < TPW; ++t) {
        float d = bestd[t];
        int   i = besti[t];
        #pragma unroll
        for (int m = 32; m >= 1; m >>= 1) {
            const float od = __shfl_xor(d, m, 64);
            const int   oi = __shfl_xor(i, m, 64);
            if (od < d || (od == d && oi < i)) { d = od; i = oi; }
        }
        if (lane == t) myidx = i;
    }

    // ---- gather values row + scatter to output ----
    if (lane < TPW) {
        const int tg = h * 64 + wave * TPW + lane;   // tuple = b*16 + n
        const int b = tg >> 4, n = tg & 15;
        const float4* vr = (const float4*)(values + ((size_t)c * K_CODES + myidx) * D_CB);
        const float4 v0 = vr[0];
        const float4 v1 = vr[1];
        float* op = out + (size_t)b * 32768 + c * 128 + n;
        op[0]   = v0.x; op[16]  = v0.y; op[32]  = v0.z; op[48]  = v0.w;
        op[64]  = v1.x; op[80]  = v1.y; op[96]  = v1.z; op[112] = v1.w;
    }
}

extern "C" void kernel_launch(void* const* d_in, const int* in_sizes, int n_in,
                              void* d_out, int out_size, void* d_ws, size_t ws_size,
                              hipStream_t stream) {
    const float* emb    = (const float*)d_in[0];
    const float* keys   = (const float*)d_in[1];
    const float* values = (const float*)d_in[2];
    float* out = (float*)d_out;
    dkvb_kernel<<<2 * C_NUM, THREADS, 0, stream>>>(emb, keys, values, out);
}

// Round 6
// 47.355 us; speedup vs baseline: 9.5214x; 1.0377x over previous
//
#include <hip/hip_runtime.h>

#define C_NUM   256
#define K_CODES 4096
#define D_CB    8
#define THREADS 512
#define WAVES   8
#define TPW     8                   // tuples per wave (64 tuples/block)
#define CHUNKS  (K_CODES / 64)      // 64 chunks of 64 codes (one per lane)

__device__ __forceinline__ float rfl(float v) {
    return __int_as_float(__builtin_amdgcn_readfirstlane(__float_as_int(v)));
}

__global__ __launch_bounds__(THREADS, 2)
void dkvb_kernel(const float* __restrict__ emb,
                 const float* __restrict__ keys,
                 const float* __restrict__ values,
                 float* __restrict__ out) {
    __shared__ float xs[64][D_CB];   // 2 KB

    const int bid  = blockIdx.x;
    const int c    = bid & 255;      // codebook; bid and bid+256 share XCD (256%8==0)
    const int h    = bid >> 8;       // tuple half: 0 -> tuples 0..63, 1 -> 64..127
    const int tid  = threadIdx.x;
    const int wave = tid >> 6;
    const int lane = tid & 63;

    // ---- stage this block's 64 tuples of x into LDS (one element/thread) ----
    // x[t][j] = emb[(t>>4)*32768 + c*128 + j*16 + (t&15)]
    {
        const int tl = tid >> 3, j = tid & 7;
        const int tg = h * 64 + tl;
        xs[tl][j] = emb[(size_t)(tg >> 4) * 32768 + c * 128 + j * 16 + (tg & 15)];
    }
    __syncthreads();

    // ---- x into SGPRs: wave-uniform, forced scalar via readfirstlane ----
    float x[TPW][8];
    #pragma unroll
    for (int t = 0; t < TPW; ++t) {
        #pragma unroll
        for (int j = 0; j < 8; ++j) x[t][j] = rfl(xs[wave * TPW + t][j]);
    }

    float bestd[TPW];
    int   besti[TPW];
    #pragma unroll
    for (int t = 0; t < TPW; ++t) { bestd[t] = 3.4028235e38f; besti[t] = 0; }

    // ---- scan all 4096 codes; lane l owns codes {l, 64+l, ...} ----
    // dist' = k2 - 2*dot  (x2 dropped: constant per tuple, argmin-equivalent)
    const float4* kb = (const float4*)(keys + (size_t)c * K_CODES * D_CB);
    float4 a0 = kb[lane * 2];
    float4 a1 = kb[lane * 2 + 1];
    for (int ch = 0; ch < CHUNKS; ++ch) {
        const int nc = (ch + 1 < CHUNKS) ? (ch + 1) : ch;
        const float4 b0 = kb[nc * 128 + lane * 2];
        const float4 b1 = kb[nc * 128 + lane * 2 + 1];

        const int code = ch * 64 + lane;
        float k2 = a0.x * a0.x;
        k2 = fmaf(a0.y, a0.y, k2);
        k2 = fmaf(a0.z, a0.z, k2);
        k2 = fmaf(a0.w, a0.w, k2);
        k2 = fmaf(a1.x, a1.x, k2);
        k2 = fmaf(a1.y, a1.y, k2);
        k2 = fmaf(a1.z, a1.z, k2);
        k2 = fmaf(a1.w, a1.w, k2);

        #pragma unroll
        for (int t = 0; t < TPW; ++t) {
            float d = x[t][0] * a0.x;          // v_mul: sgpr * vgpr
            d = fmaf(x[t][1], a0.y, d);        // v_fmac: sgpr, vgpr, acc
            d = fmaf(x[t][2], a0.z, d);
            d = fmaf(x[t][3], a0.w, d);
            d = fmaf(x[t][4], a1.x, d);
            d = fmaf(x[t][5], a1.y, d);
            d = fmaf(x[t][6], a1.z, d);
            d = fmaf(x[t][7], a1.w, d);
            const float dist = fmaf(d, -2.0f, k2);
            const bool lt = dist < bestd[t];
            bestd[t] = lt ? dist : bestd[t];
            besti[t] = lt ? code : besti[t];
        }
        a0 = b0; a1 = b1;
    }

    // ---- cross-lane argmin per tuple (tie -> smaller index == numpy) ----
    int myidx = 0;
    #pragma unroll
    for (int t = 0; t < TPW; ++t) {
        float d = bestd[t];
        int   i = besti[t];
        #pragma unroll
        for (int m = 32; m >= 1; m >>= 1) {
            const float od = __shfl_xor(d, m, 64);
            const int   oi = __shfl_xor(i, m, 64);
            if (od < d || (od == d && oi < i)) { d = od; i = oi; }
        }
        if (lane == t) myidx = i;
    }

    // ---- gather values row + scatter to output ----
    if (lane < TPW) {
        const int tg = h * 64 + wave * TPW + lane;   // tuple = b*16 + n
        const int b = tg >> 4, n = tg & 15;
        const float4* vr = (const float4*)(values + ((size_t)c * K_CODES + myidx) * D_CB);
        const float4 v0 = vr[0];
        const float4 v1 = vr[1];
        float* op = out + (size_t)b * 32768 + c * 128 + n;
        op[0]   = v0.x; op[16]  = v0.y; op[32]  = v0.z; op[48]  = v0.w;
        op[64]  = v1.x; op[80]  = v1.y; op[96]  = v1.z; op[112] = v1.w;
    }
}

extern "C" void kernel_launch(void* const* d_in, const int* in_sizes, int n_in,
                              void* d_out, int out_size, void* d_ws, size_t ws_size,
                              hipStream_t stream) {
    const float* emb    = (const float*)d_in[0];
    const float* keys   = (const float*)d_in[1];
    const float* values = (const float*)d_in[2];
    float* out = (float*)d_out;
    dkvb_kernel<<<2 * C_NUM, THREADS, 0, stream>>>(emb, keys, values, out);
}